// Round 3
// baseline (6845.544 us; speedup 1.0000x reference)
//
#include <hip/hip_runtime.h>

#define NWG     256
#define TPB     256
#define NL0     128          // WGs [0,128) = layer0, [128,256) = layer1
#define T_STEPS 1024
#define HD      1024
#define DIN     256
#define K0      1280         // DIN + HD   (80 K16-slices)
#define K1      2048         // HD + HD    (128 K16-slices)

// LDS map (bytes): Ws [32][KD] bf16 XOR-swizzled (no pad), then reduction
// scratch [dst4][src3][64][8]f32, then pack [64][8]bf16.
#define SCR_OFF   (32*K1*2)            // 131072
#define SCR_BYTES (4*3*64*8*4)         // 24576
#define PACK_OFF  (SCR_OFF + SCR_BYTES)
#define SMEM_BYTES (PACK_OFF + 64*16)  // 156,672  (<= 160 KiB)

#define HSLAB_BYTES 131072ull            // one h snapshot: 128 planes x 64 batch x 8 bf16
#define HSLAB_U64   16384
#define HIST_DEPTH  1025                 // slot(t)=(t+1)%1025 never wraps in 1024 steps
#define HIST_BYTES  (HIST_DEPTH*HSLAB_BYTES)   // 134,348,800
#define X8_BYTES    33554432ull
#define FLAGS_BYTES 32768ull

typedef float  f32x4  __attribute__((ext_vector_type(4)));
typedef float  f32x16 __attribute__((ext_vector_type(16)));
typedef __bf16 bf16x8 __attribute__((ext_vector_type(8)));
typedef int    i32x4  __attribute__((ext_vector_type(4)));
typedef unsigned long long u64;

__device__ __forceinline__ unsigned short f2bf(float f){
  union { float f; unsigned u; } a; a.f = f;
  unsigned u = a.u;
  u += 0x7fffu + ((u >> 16) & 1u);   // RNE
  return (unsigned short)(u >> 16);
}
__device__ __forceinline__ float sigmf(float x){ return 1.0f/(1.0f + __expf(-x)); }
__device__ __forceinline__ float tanhf_fast(float x){ return 2.0f*sigmf(2.0f*x) - 1.0f; }

// coherent (MALL-level, cross-XCD) accessors — per-access, no L2 invalidation
__device__ __forceinline__ u64 ld64c(const u64* p){
  return __hip_atomic_load(p, __ATOMIC_RELAXED, __HIP_MEMORY_SCOPE_AGENT);
}
__device__ __forceinline__ unsigned ldflag(const unsigned* p){
  return __hip_atomic_load(p, __ATOMIC_RELAXED, __HIP_MEMORY_SCOPE_AGENT);
}
__device__ __forceinline__ void stflag(unsigned* p, unsigned v){
  __hip_atomic_store(p, v, __ATOMIC_RELAXED, __HIP_MEMORY_SCOPE_AGENT);
}
// 16B coherent write-through store (full lines: fast drain, no RMW at MALL)
__device__ __forceinline__ void st128c(void* p, i32x4 v){
  asm volatile("global_store_dwordx4 %0, %1, off sc0 sc1" :: "v"(p), "v"(v) : "memory");
}

// x [B,T,D] fp32 -> X8 bf16 in [T][D/8][B][8]
__global__ void xpose_kernel(const float* __restrict__ x, unsigned short* __restrict__ X8){
  int idx   = blockIdx.x*256 + threadIdx.x;
  int t     = idx >> 11;
  int rem   = idx & 2047;
  int plane = rem >> 6;
  int b     = rem & 63;
  const float* src = x + ((size_t)b << 18) + (t << 8) + (plane << 3);
  unsigned short tmp[8];
  #pragma unroll
  for (int j = 0; j < 8; ++j) tmp[j] = f2bf(src[j]);
  int4 v; __builtin_memcpy(&v, tmp, 16);
  ((int4*)X8)[idx] = v;
}

// 32x32x16 MFMA layout: A lane l: row=l&31, k=8*(l>>5)+e. B lane l: batch-col
// = l&31 (+32 for tile1), k=8*(l>>5)+e. C/D: col(batch)=lane&31,
// row=(reg&3)+8*(reg>>2)+4*(lane>>5). A-row r encodes gate=r&3, outcol=r>>2
// (same weight convention as previous rounds). 4-way K-split: wave wv owns
// slices s ≡ wv (mod 4); each A-fragment read ONCE feeds both batch tiles.
template<bool H0C, bool H1C>
__global__ void __launch_bounds__(TPB, 1)
lstm_mega(const float* __restrict__ Wih0, const float* __restrict__ Whh0,
          const float* __restrict__ bih0, const float* __restrict__ bhh0,
          const float* __restrict__ Wih1, const float* __restrict__ Whh1,
          const float* __restrict__ bih1, const float* __restrict__ bhh1,
          const unsigned short* __restrict__ X8,
          unsigned* flags, unsigned* gen,
          u64* H0, u64* H1, int d0, int d1,
          float* __restrict__ out)
{
  extern __shared__ char smem[];
  unsigned short* Ws = (unsigned short*)smem;
  float*          Sc = (float*)(smem + SCR_OFF);
  unsigned short* Pk = (unsigned short*)(smem + PACK_OFF);

  const int tid   = threadIdx.x;
  const int wg    = blockIdx.x;
  const int layer = (wg >= NL0);
  const int wgl   = layer ? wg - NL0 : wg;
  const int KD    = layer ? K1  : K0;
  const int dlen  = layer ? HD  : DIN;
  const char* X8b = (const char*)X8;

  // ---- stage 32 gate-rows into LDS, bf16, XOR-swizzled (conflict-free reads) ----
  {
    const float* Wih = layer ? Wih1 : Wih0;
    const float* Whh = layer ? Whh1 : Whh0;
    for (int m = 0; m < 32; ++m){
      int gr = (m & 3)*HD + wgl*8 + (m >> 2);      // gate-major global row
      const float* ar = Wih + (size_t)gr*dlen;
      const float* br = Whh + (size_t)gr*HD;
      unsigned short* row = Ws + m*KD;
      const int sw = (m & 7) << 3;                 // 16B-granule XOR
      for (int k = tid; k < KD; k += TPB)
        row[k ^ sw] = f2bf(k < dlen ? ar[k] : br[k - dlen]);
    }
  }
  __syncthreads();

  const int lane  = tid & 63;
  const int wv    = tid >> 6;
  const int hi    = lane >> 5;        // k-half for A/B frags; row-half for C
  const int ln31  = lane & 31;
  const unsigned short* Arow = Ws + ln31*KD;
  const int axor  = (lane & 7) << 3;  // row r=l&31 -> r&7 = lane&7

  // thread-owned output cells after reduction: wave wv owns reg-block rb=wv&1
  // of tile tau=wv>>1. cell cols: c0 = 4*rb + hi, c1 = c0 + 2. batch = tau*32+ln31.
  const int rbo  = wv & 1;
  const int bat  = (wv >> 1)*32 + ln31;
  const int c0   = 4*rbo + hi;
  const int c1   = c0 + 2;

  float bias8[8];
  {
    const float* bi = layer ? bih1 : bih0;
    const float* bh = layer ? bhh1 : bhh0;
    #pragma unroll
    for (int g = 0; g < 4; ++g){
      bias8[g]     = bi[g*HD + wgl*8 + c0] + bh[g*HD + wgl*8 + c0];
      bias8[4 + g] = bi[g*HD + wgl*8 + c1] + bh[g*HD + wgl*8 + c1];
    }
  }

  float cst[2] = {0.f, 0.f};
  float hv[2]  = {0.f, 0.f};
  f32x16 acc0, acc1;                  // tile0 (batches 0-31), tile1 (32-63)

  // chunk = 4 owned slices x 2 tiles = 16 u64 in flight
  auto LDC = [&](const char* slab, int j0, int sOff, bool coh, u64* d){
    #pragma unroll
    for (int jj = 0; jj < 4; ++jj){
      const int sp = 4*(j0 + jj) + wv - sOff;          // plane-pair in slab
      const char* p0 = slab + (((2*sp + hi)*64 + ln31) << 4);
      const u64* pa = (const u64*)p0;
      const u64* pb = (const u64*)(p0 + 512);          // tile1: +32 batches
      d[4*jj+0] = coh ? ld64c(pa)     : pa[0];
      d[4*jj+1] = coh ? ld64c(pa + 1) : pa[1];
      d[4*jj+2] = coh ? ld64c(pb)     : pb[0];
      d[4*jj+3] = coh ? ld64c(pb + 1) : pb[1];
    }
  };
  auto CHUNK = [&](int j0, u64* d){
    #pragma unroll
    for (int jj = 0; jj < 4; ++jj){
      const int s = 4*(j0 + jj) + wv;
      bf16x8 a, b0, b1;
      __builtin_memcpy(&a, Arow + ((16*s + 8*hi) ^ axor), 16);
      u64 q0[2] = {d[4*jj+0], d[4*jj+1]};
      u64 q1[2] = {d[4*jj+2], d[4*jj+3]};
      __builtin_memcpy(&b0, q0, 16);
      __builtin_memcpy(&b1, q1, 16);
      acc0 = __builtin_amdgcn_mfma_f32_32x32x16_bf16(a, b0, acc0, 0, 0, 0);
      acc1 = __builtin_amdgcn_mfma_f32_32x32x16_bf16(a, b1, acc1, 0, 0, 0);
    }
  };

  // ---- flag machinery (monotonic; seen-cache skips proven polls) ----
  unsigned seenA = 0, seenB = 0;
  auto waitL0 = [&](unsigned ep){
    if (tid < NL0 && seenA < ep){
      const unsigned* p = &flags[tid*16];
      unsigned v = ldflag(p);
      while (v < ep){ __builtin_amdgcn_s_sleep(1); v = ldflag(p); }
      seenA = v;
    }
    __syncthreads();
  };
  auto waitL1 = [&](unsigned ep){
    if (tid < NL0 && seenB < ep){
      const unsigned* p = &flags[(NL0 + tid)*16];
      unsigned v = ldflag(p);
      while (v < ep){ __builtin_amdgcn_s_sleep(1); v = ldflag(p); }
      seenB = v;
    }
    __syncthreads();
  };
  auto postF = [&](unsigned ep){
    asm volatile("s_waitcnt vmcnt(0)" ::: "memory");  // sc stores at MALL
    __syncthreads();                                  // whole WG drained
    if (tid == 0) stflag(&flags[wg*16], ep);
  };
  auto waitAll = [&](unsigned ep){                    // legacy full join (tier0)
    while (ldflag(&flags[tid*16]) < ep) __builtin_amdgcn_s_sleep(1);
    __syncthreads();
  };

  u64 B0[16], B1[16], B2[16];   // depth-3 chunk ring (proven idiom)

  // 4-way K-reduction through LDS + gates + LDS-pack + one 16B store per batch
  auto epilogue = [&](u64* Hw, int wd, int t){
    // write the 3 partners' owned 8-f32 slices
    #pragma unroll
    for (int dst = 0; dst < 4; ++dst){
      if (dst == wv) continue;                         // runtime guard only
      const int slot = (wv - dst - 1) & 3;             // 0..2, unique per (dst,src)
      const int rb   = dst & 1;                        // compile-time
      const f32x16 S = (dst & 2) ? acc1 : acc0;        // compile-time pick
      f32x4 lo = { S[8*rb+0], S[8*rb+1], S[8*rb+2], S[8*rb+3] };
      f32x4 hb = { S[8*rb+4], S[8*rb+5], S[8*rb+6], S[8*rb+7] };
      float* q = Sc + ((dst*3 + slot)*64 + lane)*8;
      *(f32x4*)(q)     = lo;
      *(f32x4*)(q + 4) = hb;
    }
    __syncthreads();
    // own slice + 3 partner slices
    f32x4 vlo, vhi;
    if      (wv == 0){ vlo = (f32x4){acc0[0],acc0[1],acc0[2],acc0[3]};
                       vhi = (f32x4){acc0[4],acc0[5],acc0[6],acc0[7]}; }
    else if (wv == 1){ vlo = (f32x4){acc0[8],acc0[9],acc0[10],acc0[11]};
                       vhi = (f32x4){acc0[12],acc0[13],acc0[14],acc0[15]}; }
    else if (wv == 2){ vlo = (f32x4){acc1[0],acc1[1],acc1[2],acc1[3]};
                       vhi = (f32x4){acc1[4],acc1[5],acc1[6],acc1[7]}; }
    else             { vlo = (f32x4){acc1[8],acc1[9],acc1[10],acc1[11]};
                       vhi = (f32x4){acc1[12],acc1[13],acc1[14],acc1[15]}; }
    #pragma unroll
    for (int ss = 0; ss < 3; ++ss){
      const float* q = Sc + ((wv*3 + ss)*64 + lane)*8;
      vlo += *(const f32x4*)(q);
      vhi += *(const f32x4*)(q + 4);
    }
    // gates: vlo = cell(c0) gates i,f,g,o; vhi = cell(c1)
    {
      float ii = sigmf(vlo[0] + bias8[0]);
      float ff = sigmf(vlo[1] + bias8[1]);
      float gg = tanhf_fast(vlo[2] + bias8[2]);
      float oo = sigmf(vlo[3] + bias8[3]);
      cst[0] = ff*cst[0] + ii*gg;
      hv[0]  = oo*tanhf_fast(cst[0]);
      ii = sigmf(vhi[0] + bias8[4]);
      ff = sigmf(vhi[1] + bias8[5]);
      gg = tanhf_fast(vhi[2] + bias8[6]);
      oo = sigmf(vhi[3] + bias8[7]);
      cst[1] = ff*cst[1] + ii*gg;
      hv[1]  = oo*tanhf_fast(cst[1]);
    }
    Pk[bat*8 + c0] = f2bf(hv[0]);
    Pk[bat*8 + c1] = f2bf(hv[1]);
    __syncthreads();
    if (tid < 64){
      i32x4 v; __builtin_memcpy(&v, Pk + tid*8, 16);
      char* wbase = (char*)(Hw + (size_t)((t+1) % wd)*HSLAB_U64);
      st128c(wbase + ((wgl*64 + tid) << 4), v);
    }
  };

  // ---- layer 0 step: gates = W0 @ [x_t ; h0(t-1)] ----
  // slices: x = s 0..15 (1 chunk/wave, j0=0), h = s 16..79 (4 chunks, j0=4..16)
  auto step0 = [&](int t, bool dec){
    acc0 = (f32x16)(0.f); acc1 = (f32x16)(0.f);
    const char* xb = X8b + ((size_t)t << 15);
    const char* hb = (const char*)(H0 + (size_t)(t % d0)*HSLAB_U64);
    LDC(xb, 0, 0, false, B0);                 // x: no dependency
    if (dec) waitL0((unsigned)t);             // own-group join: h0(t-1) ready
    LDC(hb, 4, 16, H0C, B1);
    LDC(hb, 8, 16, H0C, B2);
    CHUNK(0, B0);
    LDC(hb, 12, 16, H0C, B0);
    CHUNK(4, B1);
    LDC(hb, 16, 16, H0C, B1);
    CHUNK(8, B2);
    CHUNK(12, B0);
    CHUNK(16, B1);
    epilogue(H0, d0, t);
  };

  // ---- layer 1 step: gates = W1 @ [y0(t) ; h1(t-1)] ----
  // slices: y = s 0..63 (4 chunks, j0=0..12), h = s 64..127 (4 chunks, j0=16..28)
  auto step1 = [&](int t, bool dec){
    acc0 = (f32x16)(0.f); acc1 = (f32x16)(0.f);
    const char* yb = (const char*)(H0 + (size_t)((t+1) % d0)*HSLAB_U64);
    const char* hb = (const char*)(H1 + (size_t)(t % d1)*HSLAB_U64);
    if (dec) waitL0((unsigned)(t+1));   // y0(t) ready — instant once L0 ahead
    LDC(yb, 0, 0, H0C, B0);
    LDC(yb, 4, 0, H0C, B1);
    LDC(yb, 8, 0, H0C, B2);
    CHUNK(0, B0);
    LDC(yb, 12, 0, H0C, B0);
    CHUNK(4, B1);
    CHUNK(8, B2);
    if (dec) waitL1((unsigned)t);       // the real join: h1(t-1) ready
    LDC(hb, 16, 64, H1C, B1);
    LDC(hb, 20, 64, H1C, B2);
    CHUNK(12, B0);                      // y chunk 3 hides h1 MALL latency
    LDC(hb, 24, 64, H1C, B0);
    CHUNK(16, B1);
    LDC(hb, 28, 64, H1C, B1);
    CHUNK(20, B2);
    CHUNK(24, B0);
    CHUNK(28, B1);
    epilogue(H1, d1, t);
  };

  const bool dec = (d0 >= T_STEPS + 1);  // deep y0 ring => decoupled schedule
  if (!layer){
    if (dec){
      for (int s = 0; s < T_STEPS; ++s){ step0(s, true); postF((unsigned)(s+1)); }
    } else {
      for (int s = 0; s < T_STEPS; ++s){
        step0(s, false); postF((unsigned)(s+1)); waitAll((unsigned)(s+1));
      }
    }
  } else {
    if (dec){
      for (int t = 0; t < T_STEPS; ++t){ step1(t, true); postF((unsigned)(t+1)); }
    } else {
      for (int s = 0; s < T_STEPS; ++s){
        if (s > 0) step1(s-1, false);
        postF((unsigned)(s+1)); waitAll((unsigned)(s+1));
      }
      step1(T_STEPS-1, false);
    }
  }

  // out = [h0 | h1 | c0 | c1], each [B=64, H=1024] fp32
  {
    const int base = layer ? 65536 : 0;
    out[base          + bat*HD + wgl*8 + c0] = hv[0];
    out[base          + bat*HD + wgl*8 + c1] = hv[1];
    out[base + 131072 + bat*HD + wgl*8 + c0] = cst[0];
    out[base + 131072 + bat*HD + wgl*8 + c1] = cst[1];
  }
}

extern "C" void kernel_launch(void* const* d_in, const int* in_sizes, int n_in,
                              void* d_out, int out_size, void* d_ws, size_t ws_size,
                              hipStream_t stream)
{
  const float* x    = (const float*)d_in[0];
  const float* Wih0 = (const float*)d_in[1];
  const float* Whh0 = (const float*)d_in[2];
  const float* bih0 = (const float*)d_in[3];
  const float* bhh0 = (const float*)d_in[4];
  const float* Wih1 = (const float*)d_in[5];
  const float* Whh1 = (const float*)d_in[6];
  const float* bih1 = (const float*)d_in[7];
  const float* bhh1 = (const float*)d_in[8];
  float* out = (float*)d_out;

  char* ws = (char*)d_ws;
  unsigned* flags = (unsigned*)ws;
  unsigned* gen   = (unsigned*)(ws + 16384);

  const size_t need2 = FLAGS_BYTES + 2*HIST_BYTES + X8_BYTES;               // ~302 MB
  const size_t need1 = FLAGS_BYTES + HIST_BYTES + 2*HSLAB_BYTES + X8_BYTES; // ~168 MB

  u64 *H0p, *H1p; unsigned short* X8p; int d0, d1, tier;
  if (ws_size >= need2){
    tier = 2; d0 = HIST_DEPTH; d1 = HIST_DEPTH;
    H0p = (u64*)(ws + FLAGS_BYTES);
    H1p = (u64*)(ws + FLAGS_BYTES + HIST_BYTES);
    X8p = (unsigned short*)(ws + FLAGS_BYTES + 2*HIST_BYTES);
  } else if (ws_size >= need1){
    tier = 1; d0 = HIST_DEPTH; d1 = 2;
    H0p = (u64*)(ws + FLAGS_BYTES);
    H1p = (u64*)(ws + FLAGS_BYTES + HIST_BYTES);
    X8p = (unsigned short*)(ws + FLAGS_BYTES + HIST_BYTES + 2*HSLAB_BYTES);
  } else {
    tier = 0; d0 = 2; d1 = 2;
    H0p = (u64*)(ws + FLAGS_BYTES);
    H1p = (u64*)(ws + FLAGS_BYTES + 2*HSLAB_BYTES);
    X8p = (unsigned short*)(ws + FLAGS_BYTES + 4*HSLAB_BYTES);
  }

  // zero flags + slot 0 of each h buffer (initial state h(-1)=0)
  hipMemsetAsync(flags, 0, FLAGS_BYTES, stream);
  hipMemsetAsync(H0p, 0, HSLAB_BYTES, stream);
  hipMemsetAsync(H1p, 0, HSLAB_BYTES, stream);
  xpose_kernel<<<8192, 256, 0, stream>>>(x, X8p);

  void* fn = (tier == 2) ? (void*)&lstm_mega<false,false>
           : (tier == 1) ? (void*)&lstm_mega<false,true>
                         : (void*)&lstm_mega<true,true>;
  hipFuncSetAttribute(fn, hipFuncAttributeMaxDynamicSharedMemorySize, SMEM_BYTES);

  const unsigned short* X8c = X8p;
  void* args[] = {(void*)&Wih0,(void*)&Whh0,(void*)&bih0,(void*)&bhh0,
                  (void*)&Wih1,(void*)&Whh1,(void*)&bih1,(void*)&bhh1,
                  (void*)&X8c,(void*)&flags,(void*)&gen,
                  (void*)&H0p,(void*)&H1p,(void*)&d0,(void*)&d1,(void*)&out};
  hipError_t err = hipLaunchCooperativeKernel(fn, dim3(NWG), dim3(TPB),
                                              args, SMEM_BYTES, stream);
  if (err != hipSuccess){
    // Fallback: plain launch. 256 WGs x ~153KB LDS => 1 WG/CU, grid == CU
    // count, all WGs co-resident by capacity.
    if (tier == 2)
      lstm_mega<false,false><<<dim3(NWG), dim3(TPB), SMEM_BYTES, stream>>>(
        Wih0,Whh0,bih0,bhh0,Wih1,Whh1,bih1,bhh1,X8c,flags,gen,H0p,H1p,d0,d1,out);
    else if (tier == 1)
      lstm_mega<false,true><<<dim3(NWG), dim3(TPB), SMEM_BYTES, stream>>>(
        Wih0,Whh0,bih0,bhh0,Wih1,Whh1,bih1,bhh1,X8c,flags,gen,H0p,H1p,d0,d1,out);
    else
      lstm_mega<true,true><<<dim3(NWG), dim3(TPB), SMEM_BYTES, stream>>>(
        Wih0,Whh0,bih0,bhh0,Wih1,Whh1,bih1,bhh1,X8c,flags,gen,H0p,H1p,d0,d1,out);
  }
}